// Round 11
// baseline (412.793 us; speedup 1.0000x reference)
//
#include <hip/hip_runtime.h>
#include <hip/hip_cooperative_groups.h>
#include <stdint.h>

namespace cg = cooperative_groups;

// ---------------------------------------------------------------------------
// NeighborSearch: data[n,3], queries[m,3], radius scalar.
// Out layout (int32): [0, m*n)   neighbors_index (compacted front, -1 pad)
//                     [m*n, m*n+m+1) row_splits (exclusive prefix of counts)
//
// Fast path (n==m==8192): ONE cooperative kernel, 1024 blocks x 256
// (4 blocks/CU x 256 CU = co-resident). Phases:
//   0: zero counts + steal counters. grid.sync.
//   A: even blocks: readlane/ballot count (proven R10), 16 units each;
//      odd blocks: -1 fill via work-stealing 1MB chunks over [C0,64M);
//      counters join stealing when done. grid.sync.
//   B: block 0: scan counts->row_splits; others drain reserved fill pool.
//      grid.sync.
//   C: emit 8 queries/block from query-major masks + tail fill [L,C0).
// Fallback: proven R10 4-dispatch pipeline (also used if coop launch fails).
// ---------------------------------------------------------------------------

#define N8 8192
#define C0 2097152                    // fill boundary (ints) = 8 MB
#define C04 (C0 / 4)                  // 524288 int4
#define N4TOT ((size_t)N8 * N8 / 4)   // 16777216 int4
#define CHUNK 65536                   // int4 per steal chunk (1 MB)
#define NCHA 232                      // phase-A chunks
#define NCHB 16                       // phase-B chunks (total 248 exactly)

__device__ __forceinline__ float next_up(float x) {
    return __uint_as_float(__float_as_uint(x) + 1u);
}
__device__ __forceinline__ float next_down(float x) {
    return __uint_as_float(__float_as_uint(x) - 1u);
}

// Largest float T such that correctly-rounded sqrt(T) <= r (r > 0).
// (u <= T) <=> (sqrt_rn(max(u,0)) <= r), since sqrt_rn is monotone.
__device__ __forceinline__ float sq_threshold(float r) {
    float T = __fmul_rn(r, r);
    while (__fsqrt_rn(T) > r) T = next_down(T);
    while (__fsqrt_rn(next_up(T)) <= r) T = next_up(T);
    return T;
}

// Reference arithmetic, exactly (no contraction).
__device__ __forceinline__ float pair_metric(float qx, float qy, float qz, float q2,
                                             float dx, float dy, float dz) {
    float d2 = __fadd_rn(__fadd_rn(__fmul_rn(dx, dx), __fmul_rn(dy, dy)),
                         __fmul_rn(dz, dz));
    float dot = __builtin_fmaf(qz, dz, __builtin_fmaf(qy, dy, __fmul_rn(qx, dx)));
    return __fsub_rn(__fadd_rn(q2, d2), __fmul_rn(2.0f, dot));
}

__device__ __forceinline__ float bc_lane(float x, int j) {
    return __int_as_float(__builtin_amdgcn_readlane(__float_as_int(x), j));
}

// One count unit u: chunk c=u>>6 (64 points, lane=point), group g=u&63
// (queries [g*128,(g+1)*128)). Proven R10 phase-A body.
__device__ __forceinline__ void count_unit(
    int u, const float* __restrict__ data, const float* __restrict__ queries,
    float T, unsigned long long* __restrict__ masks, int* __restrict__ counts) {
    int lane = threadIdx.x & 63;
    int c = u >> 6;
    int g = u & 63;
    int p = c * 64 + lane;
    float dx = data[3 * p + 0], dy = data[3 * p + 1], dz = data[3 * p + 2];
    float d2 = __fadd_rn(__fadd_rn(__fmul_rn(dx, dx), __fmul_rn(dy, dy)),
                         __fmul_rn(dz, dz));
    for (int s = 0; s < 2; ++s) {
        int qbase = g * 128 + s * 64;
        int q = qbase + lane;
        float qx = queries[3 * q + 0], qy = queries[3 * q + 1],
              qz = queries[3 * q + 2];
        float q2 = __fadd_rn(__fadd_rn(__fmul_rn(qx, qx), __fmul_rn(qy, qy)),
                             __fmul_rn(qz, qz));
        unsigned long long parked = 0;
#pragma unroll
        for (int j = 0; j < 64; ++j) {
            float Qx = bc_lane(qx, j), Qy = bc_lane(qy, j);
            float Qz = bc_lane(qz, j), Q2 = bc_lane(q2, j);
            float dot = __builtin_fmaf(Qz, dz,
                          __builtin_fmaf(Qy, dy, __fmul_rn(Qx, dx)));
            float uu = __fsub_rn(__fadd_rn(Q2, d2), __fmul_rn(2.0f, dot));
            unsigned long long mk = __ballot(uu <= T);
            if (lane == j) parked = mk;   // lane j keeps query qbase+j
        }
        masks[(size_t)(qbase + lane) * 128 + c] = parked;  // query-major
        atomicAdd(&counts[qbase + lane], __popcll(parked));
    }
}

// Work-stealing -1 fill: chunks [choff, choff+nch) of [C0, 64M).
__device__ __forceinline__ void steal_fill(int* __restrict__ out_idx,
                                           int* __restrict__ ctr, int nch,
                                           int choff, int* s_ch) {
    int4* out4 = (int4*)out_idx;
    const int4 v = make_int4(-1, -1, -1, -1);
    for (;;) {
        if (threadIdx.x == 0) *s_ch = atomicAdd(ctr, 1);
        __syncthreads();
        int ch = *s_ch;
        __syncthreads();
        if (ch >= nch) break;
        size_t base = (size_t)C04 + (size_t)(ch + choff) * CHUNK;
#pragma unroll 4
        for (int k = 0; k < CHUNK / 256; ++k)
            out4[base + (size_t)k * 256 + threadIdx.x] = v;
    }
}

// ======================= cooperative all-in-one kernel ======================

__global__ __launch_bounds__(256, 4) void coop_all(
    const float* __restrict__ data, const float* __restrict__ queries,
    const float* __restrict__ radius_p, int* __restrict__ out_idx,
    unsigned long long* __restrict__ masks, int* __restrict__ counts,
    int* __restrict__ ctrA, int* __restrict__ ctrB, int* __restrict__ rs) {
    cg::grid_group grid = cg::this_grid();
    int bid = blockIdx.x;
    int tid = threadIdx.x;
    int lane = tid & 63;
    int wv = tid >> 6;
    __shared__ int s_ch;
    __shared__ int part[256];

    // ---- phase 0: init ----
    if (bid < 32) counts[bid * 256 + tid] = 0;
    if (bid == 32 && tid == 0) *ctrA = 0;
    if (bid == 33 && tid == 0) *ctrB = 0;
    grid.sync();

    // ---- phase A: count (even blocks) overlapped with steal-fill ----
    if ((bid & 1) == 0) {
        float T = sq_threshold(radius_p[0]);
        int ub = (bid >> 1) * 16 + wv * 4;   // 512 blocks x 16 units = 8192
        for (int h = 0; h < 4; ++h)
            count_unit(ub + h, data, queries, T, masks, counts);
    }
    steal_fill(out_idx, ctrA, NCHA, 0, &s_ch);
    grid.sync();

    // ---- phase B: block 0 scans; others drain reserved fill pool ----
    if (bid == 0) {
        int s = 0;
        for (int k = 0; k < 32; ++k) s += counts[tid * 32 + k];
        part[tid] = s;
        __syncthreads();
        for (int off = 1; off < 256; off <<= 1) {
            int v = 0;
            if (tid >= off) v = part[tid - off];
            __syncthreads();
            if (tid >= off) part[tid] += v;
            __syncthreads();
        }
        int run = (tid == 0) ? 0 : part[tid - 1];
        for (int k = 0; k < 32; ++k) {
            int q = tid * 32 + k;
            rs[q] = run;
            run += counts[q];
        }
        if (tid == 255) rs[N8] = part[255];
    } else {
        steal_fill(out_idx, ctrB, NCHB, NCHA, &s_ch);
    }
    grid.sync();

    // ---- phase C: emit 8 queries/block + tail fill [L, C0) ----
    for (int s2 = 0; s2 < 2; ++s2) {
        int q = bid * 8 + wv * 2 + s2;
        unsigned long long lo = masks[(size_t)q * 128 + lane];
        unsigned long long hi = masks[(size_t)q * 128 + 64 + lane];
        int plo = __popcll(lo), phi = __popcll(hi);
        int ilo = plo, ihi = phi;
        for (int off = 1; off < 64; off <<= 1) {
            int a = __shfl_up(ilo, off, 64);
            int b = __shfl_up(ihi, off, 64);
            if (lane >= off) { ilo += a; ihi += b; }
        }
        int total_lo = __shfl(ilo, 63, 64);
        int base = rs[q];
        int pos_lo = base + ilo - plo;
        int pos_hi = base + total_lo + ihi - phi;
        int jb_lo = lane * 64, jb_hi = (64 + lane) * 64;
        while (lo) {
            int b = __builtin_ctzll(lo);
            out_idx[pos_lo++] = jb_lo + b;
            lo &= lo - 1;
        }
        while (hi) {
            int b = __builtin_ctzll(hi);
            out_idx[pos_hi++] = jb_hi + b;
            hi &= hi - 1;
        }
    }
    {
        int L = rs[N8];
        int Lr = (L + 3) & ~3;
        if (bid == 0 && tid < (Lr - L)) out_idx[L + tid] = -1;
        int4* out4 = (int4*)out_idx;
        const int4 v = make_int4(-1, -1, -1, -1);
        for (size_t i = (size_t)(Lr >> 2) + (size_t)bid * 256 + tid;
             i < (size_t)C04; i += 1024ull * 256ull)
            out4[i] = v;
    }
}

// ==================== proven R10 pipeline (fallback path) ====================

__global__ __launch_bounds__(256) void count_then_fill(
    const float* __restrict__ data, const float* __restrict__ queries,
    const float* __restrict__ radius_p, int* __restrict__ out_idx,
    unsigned long long* __restrict__ masks, int* __restrict__ counts) {
    int bid = blockIdx.x;
    int wv = threadIdx.x >> 6;
    {
        float T = sq_threshold(radius_p[0]);
        count_unit(bid * 4 + wv, data, queries, T, masks, counts);
    }
    int4* out4 = (int4*)out_idx;
    const int4 v = make_int4(-1, -1, -1, -1);
    size_t i = (size_t)C04 + (size_t)bid * 256 + threadIdx.x;
    const size_t stride = 2048ull * 256ull;
    for (; i < N4TOT; i += stride) out4[i] = v;
}

__global__ __launch_bounds__(1024) void scan_kernel2(const int* __restrict__ counts,
                                                     int* __restrict__ rs, int m) {
    __shared__ int part[1024];
    int t = threadIdx.x;
    int base = t * 8;
    int c[8];
    int s = 0;
    for (int k = 0; k < 8; ++k) {
        int p = base + k;
        c[k] = (p < m) ? counts[p] : 0;
        s += c[k];
    }
    part[t] = s;
    __syncthreads();
    for (int off = 1; off < 1024; off <<= 1) {
        int v = 0;
        if (t >= off) v = part[t - off];
        __syncthreads();
        if (t >= off) part[t] += v;
        __syncthreads();
    }
    int run = (t == 0) ? 0 : part[t - 1];
    for (int k = 0; k < 8; ++k) {
        int p = base + k;
        if (p < m) rs[p] = run;
        run += c[k];
    }
    if (t == 1023) rs[m] = part[1023];
}

__global__ __launch_bounds__(256) void emit_fill_tail(
    const unsigned long long* __restrict__ masks, const int* __restrict__ rs,
    int* __restrict__ out_idx) {
    int wave = threadIdx.x >> 6;
    int lane = threadIdx.x & 63;
    int q = blockIdx.x * 4 + wave;

    unsigned long long lo = masks[(size_t)q * 128 + lane];
    unsigned long long hi = masks[(size_t)q * 128 + 64 + lane];
    int plo = __popcll(lo), phi = __popcll(hi);
    int ilo = plo, ihi = phi;
    for (int off = 1; off < 64; off <<= 1) {
        int a = __shfl_up(ilo, off, 64);
        int b = __shfl_up(ihi, off, 64);
        if (lane >= off) { ilo += a; ihi += b; }
    }
    int total_lo = __shfl(ilo, 63, 64);
    int base = rs[q];
    int pos_lo = base + ilo - plo;
    int pos_hi = base + total_lo + ihi - phi;
    int jb_lo = lane * 64, jb_hi = (64 + lane) * 64;
    while (lo) {
        int b = __builtin_ctzll(lo);
        out_idx[pos_lo++] = jb_lo + b;
        lo &= lo - 1;
    }
    while (hi) {
        int b = __builtin_ctzll(hi);
        out_idx[pos_hi++] = jb_hi + b;
        hi &= hi - 1;
    }

    int L = rs[N8];
    int Lr = (L + 3) & ~3;
    if (blockIdx.x == 0 && (int)threadIdx.x < (Lr - L))
        out_idx[L + threadIdx.x] = -1;
    int4* out4 = (int4*)out_idx;
    const int4 v = make_int4(-1, -1, -1, -1);
    int i = (Lr >> 2) + blockIdx.x * 256 + threadIdx.x;
    const int stride = 2048 * 256;
    for (; i < C04; i += stride) out4[i] = v;
}

// ====================== generic fallback (round-1 path) ======================

__global__ __launch_bounds__(256) void fill_kernel(int* __restrict__ out, size_t total) {
    size_t n4 = total >> 2;
    int4* out4 = (int4*)out;
    size_t i = (size_t)blockIdx.x * blockDim.x + threadIdx.x;
    size_t stride = (size_t)gridDim.x * blockDim.x;
    const int4 v = make_int4(-1, -1, -1, -1);
    for (; i < n4; i += stride) out4[i] = v;
    if (blockIdx.x == 0 && threadIdx.x == 0) {
        for (size_t k = n4 << 2; k < total; ++k) out[k] = -1;
    }
}

__global__ __launch_bounds__(256) void count_kernel(
    const float* __restrict__ data, const float* __restrict__ queries,
    const float* __restrict__ radius_p, int n, int m, int* __restrict__ counts) {
    int q = (blockIdx.x * blockDim.x + threadIdx.x) >> 6;
    int lane = threadIdx.x & 63;
    if (q >= m) return;
    float r = radius_p[0];
    float T = sq_threshold(r);
    float qx = queries[3 * q + 0], qy = queries[3 * q + 1], qz = queries[3 * q + 2];
    float q2 = __fadd_rn(__fadd_rn(__fmul_rn(qx, qx), __fmul_rn(qy, qy)),
                         __fmul_rn(qz, qz));
    int cnt = 0;
    for (int j = lane; j < n; j += 64) {
        float u = pair_metric(qx, qy, qz, q2, data[3 * j], data[3 * j + 1], data[3 * j + 2]);
        if (u <= T) cnt++;
    }
    for (int off = 32; off > 0; off >>= 1) cnt += __shfl_down(cnt, off, 64);
    if (lane == 0) counts[q] = cnt;
}

__global__ __launch_bounds__(256) void emit_kernel(
    const float* __restrict__ data, const float* __restrict__ queries,
    const float* __restrict__ radius_p, int n, int m,
    const int* __restrict__ row_splits, int* __restrict__ out_idx) {
    int q = (blockIdx.x * blockDim.x + threadIdx.x) >> 6;
    int lane = threadIdx.x & 63;
    if (q >= m) return;
    float r = radius_p[0];
    float T = sq_threshold(r);
    float qx = queries[3 * q + 0], qy = queries[3 * q + 1], qz = queries[3 * q + 2];
    float q2 = __fadd_rn(__fadd_rn(__fmul_rn(qx, qx), __fmul_rn(qy, qy)),
                         __fmul_rn(qz, qz));
    int base = row_splits[q];
    unsigned long long lane_mask_lt = (lane == 0) ? 0ULL : (~0ULL >> (64 - lane));
    for (int j0 = 0; j0 < n; j0 += 64) {
        int j = j0 + lane;
        bool pred = false;
        if (j < n) {
            float u = pair_metric(qx, qy, qz, q2, data[3 * j], data[3 * j + 1], data[3 * j + 2]);
            pred = (u <= T);
        }
        unsigned long long mask = __ballot(pred);
        if (pred) {
            int pos = base + __popcll(mask & lane_mask_lt);
            out_idx[pos] = j;
        }
        base += __popcll(mask);
    }
}

// ===========================================================================

extern "C" void kernel_launch(void* const* d_in, const int* in_sizes, int n_in,
                              void* d_out, int out_size, void* d_ws, size_t ws_size,
                              hipStream_t stream) {
    const float* data = (const float*)d_in[0];
    const float* queries = (const float*)d_in[1];
    const float* radius = (const float*)d_in[2];
    int n = in_sizes[0] / 3;
    int m = in_sizes[1] / 3;
    int* out = (int*)d_out;
    size_t idx_count = (size_t)m * (size_t)n;
    int* row = out + idx_count;  // m+1 ints

    // ws layout: masks (8MB, query-major) | counts (32KB) | ctrA, ctrB
    size_t mask_bytes = (size_t)N8 * 128 * 8;
    size_t need = mask_bytes + N8 * 4 + 2 * sizeof(int);
    bool fast = (n == N8) && (m == N8) && (ws_size >= need);

    if (fast) {
        unsigned long long* masks = (unsigned long long*)d_ws;
        int* counts = (int*)((char*)d_ws + mask_bytes);
        int* ctrA = (int*)((char*)d_ws + mask_bytes + N8 * 4);
        int* ctrB = ctrA + 1;

        void* args[] = {(void*)&data, (void*)&queries, (void*)&radius,
                        (void*)&out,  (void*)&masks,   (void*)&counts,
                        (void*)&ctrA, (void*)&ctrB,    (void*)&row};
        hipError_t err = hipLaunchCooperativeKernel(
            (const void*)coop_all, dim3(1024), dim3(256), args, 0, stream);
        if (err == hipSuccess) return;

        // Fallback: proven R10 4-dispatch pipeline.
        hipMemsetAsync(counts, 0, N8 * sizeof(int), stream);
        count_then_fill<<<2048, 256, 0, stream>>>(data, queries, radius, out,
                                                  masks, counts);
        scan_kernel2<<<1, 1024, 0, stream>>>(counts, row, m);
        emit_fill_tail<<<2048, 256, 0, stream>>>(masks, row, out);
    } else {
        fill_kernel<<<2048, 256, 0, stream>>>(out, idx_count);
        int blocks = (m * 64 + 255) / 256;
        count_kernel<<<blocks, 256, 0, stream>>>(data, queries, radius, n, m, row);
        scan_kernel2<<<1, 1024, 0, stream>>>(row, row, m);
        emit_kernel<<<blocks, 256, 0, stream>>>(data, queries, radius, n, m, row, out);
    }
}

// Round 12
// 75.403 us; speedup vs baseline: 5.4745x; 5.4745x over previous
//
#include <hip/hip_runtime.h>
#include <stdint.h>

// ---------------------------------------------------------------------------
// NeighborSearch: data[n,3], queries[m,3], radius scalar.
// Out layout (int32): [0, m*n)   neighbors_index (compacted front, -1 pad)
//                     [m*n, m*n+m+1) row_splits (exclusive prefix of counts)
//
// Fast path (n==m==8192), 3 nodes (R10 proven structure, scan merged into K3):
//   memset: counts = 0.
//   K1 count_then_fill (2048x256, proven R10): phase A count (wave-unit
//     readlane/ballot, query-major masks, atomic counts); phase B full-machine
//     -1 int4 stream over [C0, 64M).
//   K3 scanemit_fill_tail (2048x256): per-block full scan of counts (256-wide
//     LDS scan; counts are L2-hot) -> rs written by owning blocks; emit [0,L)
//     from query-major masks (proven R9/R10 code); tail fill [L, C0).
// R11 lesson: cooperative grid.sync = 412us (machine idle ~90%). Discrete
// dispatches with ~4-6us gaps are far cheaper than coop sync on this chip.
// ---------------------------------------------------------------------------

#define N8 8192
#define C0 2097152                    // fill boundary (ints) = 8 MB
#define C04 (C0 / 4)                  // 524288 int4
#define N4TOT ((size_t)N8 * N8 / 4)   // 16777216 int4

__device__ __forceinline__ float next_up(float x) {
    return __uint_as_float(__float_as_uint(x) + 1u);
}
__device__ __forceinline__ float next_down(float x) {
    return __uint_as_float(__float_as_uint(x) - 1u);
}

// Largest float T such that correctly-rounded sqrt(T) <= r (r > 0).
// (u <= T) <=> (sqrt_rn(max(u,0)) <= r), since sqrt_rn is monotone.
__device__ __forceinline__ float sq_threshold(float r) {
    float T = __fmul_rn(r, r);
    while (__fsqrt_rn(T) > r) T = next_down(T);
    while (__fsqrt_rn(next_up(T)) <= r) T = next_up(T);
    return T;
}

// Reference arithmetic, exactly (no contraction).
__device__ __forceinline__ float pair_metric(float qx, float qy, float qz, float q2,
                                             float dx, float dy, float dz) {
    float d2 = __fadd_rn(__fadd_rn(__fmul_rn(dx, dx), __fmul_rn(dy, dy)),
                         __fmul_rn(dz, dz));
    float dot = __builtin_fmaf(qz, dz, __builtin_fmaf(qy, dy, __fmul_rn(qx, dx)));
    return __fsub_rn(__fadd_rn(q2, d2), __fmul_rn(2.0f, dot));
}

__device__ __forceinline__ float bc_lane(float x, int j) {
    return __int_as_float(__builtin_amdgcn_readlane(__float_as_int(x), j));
}

// One count unit u: chunk c=u>>6 (64 points, lane=point), group g=u&63
// (queries [g*128,(g+1)*128)). Proven R10 body.
__device__ __forceinline__ void count_unit(
    int u, const float* __restrict__ data, const float* __restrict__ queries,
    float T, unsigned long long* __restrict__ masks, int* __restrict__ counts) {
    int lane = threadIdx.x & 63;
    int c = u >> 6;
    int g = u & 63;
    int p = c * 64 + lane;
    float dx = data[3 * p + 0], dy = data[3 * p + 1], dz = data[3 * p + 2];
    float d2 = __fadd_rn(__fadd_rn(__fmul_rn(dx, dx), __fmul_rn(dy, dy)),
                         __fmul_rn(dz, dz));
    for (int s = 0; s < 2; ++s) {
        int qbase = g * 128 + s * 64;
        int q = qbase + lane;
        float qx = queries[3 * q + 0], qy = queries[3 * q + 1],
              qz = queries[3 * q + 2];
        float q2 = __fadd_rn(__fadd_rn(__fmul_rn(qx, qx), __fmul_rn(qy, qy)),
                             __fmul_rn(qz, qz));
        unsigned long long parked = 0;
#pragma unroll
        for (int j = 0; j < 64; ++j) {
            float Qx = bc_lane(qx, j), Qy = bc_lane(qy, j);
            float Qz = bc_lane(qz, j), Q2 = bc_lane(q2, j);
            float dot = __builtin_fmaf(Qz, dz,
                          __builtin_fmaf(Qy, dy, __fmul_rn(Qx, dx)));
            float uu = __fsub_rn(__fadd_rn(Q2, d2), __fmul_rn(2.0f, dot));
            unsigned long long mk = __ballot(uu <= T);
            if (lane == j) parked = mk;   // lane j keeps query qbase+j
        }
        masks[(size_t)(qbase + lane) * 128 + c] = parked;  // query-major
        atomicAdd(&counts[qbase + lane], __popcll(parked));
    }
}

// ========================= fast path (8192 x 8192) =========================

// Grid: 2048 x 256. Phase A: count (unit per wave). Phase B: fill. (Proven.)
__global__ __launch_bounds__(256) void count_then_fill(
    const float* __restrict__ data, const float* __restrict__ queries,
    const float* __restrict__ radius_p, int* __restrict__ out_idx,
    unsigned long long* __restrict__ masks, int* __restrict__ counts) {
    int bid = blockIdx.x;
    int wv = threadIdx.x >> 6;
    {
        float T = sq_threshold(radius_p[0]);
        count_unit(bid * 4 + wv, data, queries, T, masks, counts);
    }
    int4* out4 = (int4*)out_idx;
    const int4 v = make_int4(-1, -1, -1, -1);
    size_t i = (size_t)C04 + (size_t)bid * 256 + threadIdx.x;
    const size_t stride = 2048ull * 256ull;
    for (; i < N4TOT; i += stride) out4[i] = v;
}

// Grid: 2048 x 256. Per-block scan (counts L2-hot) + rs write + proven emit
// + tail fill [L, C0). Block b owns queries b*4..b*4+3 (all in one 32-chunk).
__global__ __launch_bounds__(256) void scanemit_fill_tail(
    const unsigned long long* __restrict__ masks, const int* __restrict__ counts,
    int* __restrict__ out_idx, int* __restrict__ rs) {
    __shared__ int part[256];
    __shared__ int s_cnt[32];
    __shared__ int s_base[4];
    int b = blockIdx.x;
    int t = threadIdx.x;
    int wave = t >> 6;
    int lane = t & 63;

    // ---- full scan of counts: thread t sums its 32-query chunk ----
    int s = 0;
#pragma unroll 8
    for (int k = 0; k < 32; ++k) s += counts[t * 32 + k];
    part[t] = s;
    __syncthreads();
    for (int off = 1; off < 256; off <<= 1) {
        int v = 0;
        if (t >= off) v = part[t - off];
        __syncthreads();
        if (t >= off) part[t] += v;
        __syncthreads();
    }
    int c32 = b >> 3;                 // 32-chunk holding this block's 4 queries
    if (t < 32) s_cnt[t] = counts[c32 * 32 + t];
    __syncthreads();
    if (t < 4) {
        int q = b * 4 + t;
        int excl = (c32 == 0) ? 0 : part[c32 - 1];
        int o = q & 31;
        int sum = 0;
        for (int k = 0; k < o; ++k) sum += s_cnt[k];
        int v = excl + sum;
        s_base[t] = v;
        rs[q] = v;                    // blocks collectively write rs[0..8191]
    }
    if (b == 2047 && t == 0) rs[N8] = part[255];
    __syncthreads();
    int L = part[255];

    // ---- emit (positions < L), proven R9/R10 code ----
    {
        int q = b * 4 + wave;
        unsigned long long lo = masks[(size_t)q * 128 + lane];
        unsigned long long hi = masks[(size_t)q * 128 + 64 + lane];
        int plo = __popcll(lo), phi = __popcll(hi);
        int ilo = plo, ihi = phi;
        for (int off = 1; off < 64; off <<= 1) {
            int a = __shfl_up(ilo, off, 64);
            int bsh = __shfl_up(ihi, off, 64);
            if (lane >= off) { ilo += a; ihi += bsh; }
        }
        int total_lo = __shfl(ilo, 63, 64);
        int base = s_base[wave];
        int pos_lo = base + ilo - plo;
        int pos_hi = base + total_lo + ihi - phi;
        int jb_lo = lane * 64, jb_hi = (64 + lane) * 64;
        while (lo) {
            int bt = __builtin_ctzll(lo);
            out_idx[pos_lo++] = jb_lo + bt;
            lo &= lo - 1;
        }
        while (hi) {
            int bt = __builtin_ctzll(hi);
            out_idx[pos_hi++] = jb_hi + bt;
            hi &= hi - 1;
        }
    }

    // ---- tail fill [L, C0) (K1 filled [C0, 64M)) ----
    int Lr = (L + 3) & ~3;
    if (b == 0 && t < (Lr - L)) out_idx[L + t] = -1;
    int4* out4 = (int4*)out_idx;
    const int4 v = make_int4(-1, -1, -1, -1);
    int i = (Lr >> 2) + b * 256 + t;
    const int stride = 2048 * 256;
    for (; i < C04; i += stride) out4[i] = v;
}

// ====================== generic fallback (round-1 path) ======================

__global__ __launch_bounds__(256) void fill_kernel(int* __restrict__ out, size_t total) {
    size_t n4 = total >> 2;
    int4* out4 = (int4*)out;
    size_t i = (size_t)blockIdx.x * blockDim.x + threadIdx.x;
    size_t stride = (size_t)gridDim.x * blockDim.x;
    const int4 v = make_int4(-1, -1, -1, -1);
    for (; i < n4; i += stride) out4[i] = v;
    if (blockIdx.x == 0 && threadIdx.x == 0) {
        for (size_t k = n4 << 2; k < total; ++k) out[k] = -1;
    }
}

__global__ __launch_bounds__(256) void count_kernel(
    const float* __restrict__ data, const float* __restrict__ queries,
    const float* __restrict__ radius_p, int n, int m, int* __restrict__ counts) {
    int q = (blockIdx.x * blockDim.x + threadIdx.x) >> 6;
    int lane = threadIdx.x & 63;
    if (q >= m) return;
    float r = radius_p[0];
    float T = sq_threshold(r);
    float qx = queries[3 * q + 0], qy = queries[3 * q + 1], qz = queries[3 * q + 2];
    float q2 = __fadd_rn(__fadd_rn(__fmul_rn(qx, qx), __fmul_rn(qy, qy)),
                         __fmul_rn(qz, qz));
    int cnt = 0;
    for (int j = lane; j < n; j += 64) {
        float u = pair_metric(qx, qy, qz, q2, data[3 * j], data[3 * j + 1], data[3 * j + 2]);
        if (u <= T) cnt++;
    }
    for (int off = 32; off > 0; off >>= 1) cnt += __shfl_down(cnt, off, 64);
    if (lane == 0) counts[q] = cnt;
}

__global__ __launch_bounds__(1024) void scan_kernel2(const int* __restrict__ counts,
                                                     int* __restrict__ rs, int m) {
    __shared__ int part[1024];
    int t = threadIdx.x;
    int base = t * 8;
    int c[8];
    int s = 0;
    for (int k = 0; k < 8; ++k) {
        int p = base + k;
        c[k] = (p < m) ? counts[p] : 0;
        s += c[k];
    }
    part[t] = s;
    __syncthreads();
    for (int off = 1; off < 1024; off <<= 1) {
        int v = 0;
        if (t >= off) v = part[t - off];
        __syncthreads();
        if (t >= off) part[t] += v;
        __syncthreads();
    }
    int run = (t == 0) ? 0 : part[t - 1];
    for (int k = 0; k < 8; ++k) {
        int p = base + k;
        if (p < m) rs[p] = run;
        run += c[k];
    }
    if (t == 1023) rs[m] = part[1023];
}

__global__ __launch_bounds__(256) void emit_kernel(
    const float* __restrict__ data, const float* __restrict__ queries,
    const float* __restrict__ radius_p, int n, int m,
    const int* __restrict__ row_splits, int* __restrict__ out_idx) {
    int q = (blockIdx.x * blockDim.x + threadIdx.x) >> 6;
    int lane = threadIdx.x & 63;
    if (q >= m) return;
    float r = radius_p[0];
    float T = sq_threshold(r);
    float qx = queries[3 * q + 0], qy = queries[3 * q + 1], qz = queries[3 * q + 2];
    float q2 = __fadd_rn(__fadd_rn(__fmul_rn(qx, qx), __fmul_rn(qy, qy)),
                         __fmul_rn(qz, qz));
    int base = row_splits[q];
    unsigned long long lane_mask_lt = (lane == 0) ? 0ULL : (~0ULL >> (64 - lane));
    for (int j0 = 0; j0 < n; j0 += 64) {
        int j = j0 + lane;
        bool pred = false;
        if (j < n) {
            float u = pair_metric(qx, qy, qz, q2, data[3 * j], data[3 * j + 1], data[3 * j + 2]);
            pred = (u <= T);
        }
        unsigned long long mask = __ballot(pred);
        if (pred) {
            int pos = base + __popcll(mask & lane_mask_lt);
            out_idx[pos] = j;
        }
        base += __popcll(mask);
    }
}

// ===========================================================================

extern "C" void kernel_launch(void* const* d_in, const int* in_sizes, int n_in,
                              void* d_out, int out_size, void* d_ws, size_t ws_size,
                              hipStream_t stream) {
    const float* data = (const float*)d_in[0];
    const float* queries = (const float*)d_in[1];
    const float* radius = (const float*)d_in[2];
    int n = in_sizes[0] / 3;
    int m = in_sizes[1] / 3;
    int* out = (int*)d_out;
    size_t idx_count = (size_t)m * (size_t)n;
    int* row = out + idx_count;  // m+1 ints

    // ws layout: masks (8MB, query-major) | counts (32KB)
    size_t mask_bytes = (size_t)N8 * 128 * 8;
    size_t need = mask_bytes + N8 * 4;
    bool fast = (n == N8) && (m == N8) && (ws_size >= need);

    if (fast) {
        unsigned long long* masks = (unsigned long long*)d_ws;
        int* counts = (int*)((char*)d_ws + mask_bytes);
        hipMemsetAsync(counts, 0, N8 * sizeof(int), stream);
        count_then_fill<<<2048, 256, 0, stream>>>(data, queries, radius, out,
                                                  masks, counts);
        scanemit_fill_tail<<<2048, 256, 0, stream>>>(masks, counts, out, row);
    } else {
        fill_kernel<<<2048, 256, 0, stream>>>(out, idx_count);
        int blocks = (m * 64 + 255) / 256;
        count_kernel<<<blocks, 256, 0, stream>>>(data, queries, radius, n, m, row);
        scan_kernel2<<<1, 1024, 0, stream>>>(row, row, m);
        emit_kernel<<<blocks, 256, 0, stream>>>(data, queries, radius, n, m, row, out);
    }
}

// Round 14
// 71.708 us; speedup vs baseline: 5.7566x; 1.0515x over previous
//
#include <hip/hip_runtime.h>
#include <stdint.h>

// ---------------------------------------------------------------------------
// NeighborSearch: data[n,3], queries[m,3], radius scalar.
// Out layout (int32): [0, m*n)   neighbors_index (compacted front, -1 pad)
//                     [m*n, m*n+m+1) row_splits (exclusive prefix of counts)
//
// Fast path (n==m==8192), 3 nodes:
//   memset: counts = 0.
//   K1 fused_interleave (2048x256): per wave, 31 int4 -1 stores over
//     [C0, 64M) INTERLEAVED with the 128 readlane/ballot count iterations
//     (proven R10 arithmetic). Stores drain on the memory pipe while count
//     runs on VALU -- overlap within each wave, no roles/sync.
//     R13 CRASH LESSON: the fill region is EXACTLY 31 strides of 2048x256;
//     a 32nd store walks 8MB past the output buffer (OOB -> core dump).
//     Store is guarded with k < 31.
//   K3 scanemit_fill_tail (verbatim R12): per-block scan of counts ->
//     rs, emit [0,L) from query-major masks, tail fill [L, C0).
// ---------------------------------------------------------------------------

#define N8 8192
#define C0 2097152                    // fill boundary (ints) = 8 MB
#define C04 (C0 / 4)                  // 524288 int4
#define N4TOT ((size_t)N8 * N8 / 4)   // 16777216 int4

__device__ __forceinline__ float next_up(float x) {
    return __uint_as_float(__float_as_uint(x) + 1u);
}
__device__ __forceinline__ float next_down(float x) {
    return __uint_as_float(__float_as_uint(x) - 1u);
}

// Largest float T such that correctly-rounded sqrt(T) <= r (r > 0).
// (u <= T) <=> (sqrt_rn(max(u,0)) <= r), since sqrt_rn is monotone.
__device__ __forceinline__ float sq_threshold(float r) {
    float T = __fmul_rn(r, r);
    while (__fsqrt_rn(T) > r) T = next_down(T);
    while (__fsqrt_rn(next_up(T)) <= r) T = next_up(T);
    return T;
}

// Reference arithmetic, exactly (no contraction).
__device__ __forceinline__ float pair_metric(float qx, float qy, float qz, float q2,
                                             float dx, float dy, float dz) {
    float d2 = __fadd_rn(__fadd_rn(__fmul_rn(dx, dx), __fmul_rn(dy, dy)),
                         __fmul_rn(dz, dz));
    float dot = __builtin_fmaf(qz, dz, __builtin_fmaf(qy, dy, __fmul_rn(qx, dx)));
    return __fsub_rn(__fadd_rn(q2, d2), __fmul_rn(2.0f, dot));
}

__device__ __forceinline__ float bc_lane(float x, int j) {
    return __int_as_float(__builtin_amdgcn_readlane(__float_as_int(x), j));
}

// ========================= fast path (8192 x 8192) =========================

// Grid: 2048 x 256. Wave unit u = bid*4+wv: chunk c=u>>6 (64 points, lane=
// point), group g=u&63 (queries [g*128,(g+1)*128)). Fill stores interleaved.
__global__ __launch_bounds__(256) void fused_interleave(
    const float* __restrict__ data, const float* __restrict__ queries,
    const float* __restrict__ radius_p, int* __restrict__ out_idx,
    unsigned long long* __restrict__ masks, int* __restrict__ counts) {
    int bid = blockIdx.x;
    int tid = threadIdx.x;
    int lane = tid & 63;
    int wv = tid >> 6;
    int u = bid * 4 + wv;
    int c = u >> 6;
    int g = u & 63;

    float T = sq_threshold(radius_p[0]);

    // 64 data points in registers (lane = point)
    int p = c * 64 + lane;
    float dx = data[3 * p + 0], dy = data[3 * p + 1], dz = data[3 * p + 2];
    float d2 = __fadd_rn(__fadd_rn(__fmul_rn(dx, dx), __fmul_rn(dy, dy)),
                         __fmul_rn(dz, dz));

    // both query sections' coords (lane = query within section)
    int qb0 = g * 128, qb1 = g * 128 + 64;
    int q0 = qb0 + lane, q1 = qb1 + lane;
    float qx0 = queries[3 * q0 + 0], qy0 = queries[3 * q0 + 1],
          qz0 = queries[3 * q0 + 2];
    float q20 = __fadd_rn(__fadd_rn(__fmul_rn(qx0, qx0), __fmul_rn(qy0, qy0)),
                          __fmul_rn(qz0, qz0));
    float qx1 = queries[3 * q1 + 0], qy1 = queries[3 * q1 + 1],
          qz1 = queries[3 * q1 + 2];
    float q21 = __fadd_rn(__fadd_rn(__fmul_rn(qx1, qx1), __fmul_rn(qy1, qy1)),
                          __fmul_rn(qz1, qz1));

    unsigned long long parked0 = 0, parked1 = 0;

    int4* out4 = (int4*)out_idx;
    const int4 vm1 = make_int4(-1, -1, -1, -1);
    const size_t fstride = 2048ull * 256ull;            // 524288 int4
    size_t fb = (size_t)C04 + (size_t)bid * 256 + tid;  // [C04, 2*C04)

    // Fill region [C04, N4TOT) = exactly 31 strides -> stores only for k<31.
    // ---- k in [0,16): store k | count section 0, j = 4k..4k+3 ----
    for (int k = 0; k < 16; ++k) {
        out4[fb + (size_t)k * fstride] = vm1;           // k<16<31: in bounds
#pragma unroll
        for (int jj = 0; jj < 4; ++jj) {
            int j = k * 4 + jj;
            float Qx = bc_lane(qx0, j), Qy = bc_lane(qy0, j);
            float Qz = bc_lane(qz0, j), Q2 = bc_lane(q20, j);
            float dot = __builtin_fmaf(Qz, dz,
                          __builtin_fmaf(Qy, dy, __fmul_rn(Qx, dx)));
            float uu = __fsub_rn(__fadd_rn(Q2, d2), __fmul_rn(2.0f, dot));
            unsigned long long mk = __ballot(uu <= T);
            if (lane == j) parked0 = mk;
        }
    }
    // ---- k in [16,32): store k (k<31 only) | count section 1 ----
    for (int k = 16; k < 32; ++k) {
        if (k < 31) out4[fb + (size_t)k * fstride] = vm1;
#pragma unroll
        for (int jj = 0; jj < 4; ++jj) {
            int j = (k - 16) * 4 + jj;
            float Qx = bc_lane(qx1, j), Qy = bc_lane(qy1, j);
            float Qz = bc_lane(qz1, j), Q2 = bc_lane(q21, j);
            float dot = __builtin_fmaf(Qz, dz,
                          __builtin_fmaf(Qy, dy, __fmul_rn(Qx, dx)));
            float uu = __fsub_rn(__fadd_rn(Q2, d2), __fmul_rn(2.0f, dot));
            unsigned long long mk = __ballot(uu <= T);
            if (lane == j) parked1 = mk;
        }
    }

    masks[(size_t)q0 * 128 + c] = parked0;   // query-major (proven R8+)
    masks[(size_t)q1 * 128 + c] = parked1;
    atomicAdd(&counts[q0], __popcll(parked0));
    atomicAdd(&counts[q1], __popcll(parked1));
}

// Grid: 2048 x 256. Verbatim R12: per-block scan + rs + emit + tail fill.
__global__ __launch_bounds__(256) void scanemit_fill_tail(
    const unsigned long long* __restrict__ masks, const int* __restrict__ counts,
    int* __restrict__ out_idx, int* __restrict__ rs) {
    __shared__ int part[256];
    __shared__ int s_cnt[32];
    __shared__ int s_base[4];
    int b = blockIdx.x;
    int t = threadIdx.x;
    int wave = t >> 6;
    int lane = t & 63;

    int s = 0;
#pragma unroll 8
    for (int k = 0; k < 32; ++k) s += counts[t * 32 + k];
    part[t] = s;
    __syncthreads();
    for (int off = 1; off < 256; off <<= 1) {
        int v = 0;
        if (t >= off) v = part[t - off];
        __syncthreads();
        if (t >= off) part[t] += v;
        __syncthreads();
    }
    int c32 = b >> 3;
    if (t < 32) s_cnt[t] = counts[c32 * 32 + t];
    __syncthreads();
    if (t < 4) {
        int q = b * 4 + t;
        int excl = (c32 == 0) ? 0 : part[c32 - 1];
        int o = q & 31;
        int sum = 0;
        for (int k = 0; k < o; ++k) sum += s_cnt[k];
        int v = excl + sum;
        s_base[t] = v;
        rs[q] = v;
    }
    if (b == 2047 && t == 0) rs[N8] = part[255];
    __syncthreads();
    int L = part[255];

    {
        int q = b * 4 + wave;
        unsigned long long lo = masks[(size_t)q * 128 + lane];
        unsigned long long hi = masks[(size_t)q * 128 + 64 + lane];
        int plo = __popcll(lo), phi = __popcll(hi);
        int ilo = plo, ihi = phi;
        for (int off = 1; off < 64; off <<= 1) {
            int a = __shfl_up(ilo, off, 64);
            int bsh = __shfl_up(ihi, off, 64);
            if (lane >= off) { ilo += a; ihi += bsh; }
        }
        int total_lo = __shfl(ilo, 63, 64);
        int base = s_base[wave];
        int pos_lo = base + ilo - plo;
        int pos_hi = base + total_lo + ihi - phi;
        int jb_lo = lane * 64, jb_hi = (64 + lane) * 64;
        while (lo) {
            int bt = __builtin_ctzll(lo);
            out_idx[pos_lo++] = jb_lo + bt;
            lo &= lo - 1;
        }
        while (hi) {
            int bt = __builtin_ctzll(hi);
            out_idx[pos_hi++] = jb_hi + bt;
            hi &= hi - 1;
        }
    }

    int Lr = (L + 3) & ~3;
    if (b == 0 && t < (Lr - L)) out_idx[L + t] = -1;
    int4* out4 = (int4*)out_idx;
    const int4 v = make_int4(-1, -1, -1, -1);
    int i = (Lr >> 2) + b * 256 + t;
    const int stride = 2048 * 256;
    for (; i < C04; i += stride) out4[i] = v;
}

// ====================== generic fallback (round-1 path) ======================

__global__ __launch_bounds__(256) void fill_kernel(int* __restrict__ out, size_t total) {
    size_t n4 = total >> 2;
    int4* out4 = (int4*)out;
    size_t i = (size_t)blockIdx.x * blockDim.x + threadIdx.x;
    size_t stride = (size_t)gridDim.x * blockDim.x;
    const int4 v = make_int4(-1, -1, -1, -1);
    for (; i < n4; i += stride) out4[i] = v;
    if (blockIdx.x == 0 && threadIdx.x == 0) {
        for (size_t k = n4 << 2; k < total; ++k) out[k] = -1;
    }
}

__global__ __launch_bounds__(256) void count_kernel(
    const float* __restrict__ data, const float* __restrict__ queries,
    const float* __restrict__ radius_p, int n, int m, int* __restrict__ counts) {
    int q = (blockIdx.x * blockDim.x + threadIdx.x) >> 6;
    int lane = threadIdx.x & 63;
    if (q >= m) return;
    float r = radius_p[0];
    float T = sq_threshold(r);
    float qx = queries[3 * q + 0], qy = queries[3 * q + 1], qz = queries[3 * q + 2];
    float q2 = __fadd_rn(__fadd_rn(__fmul_rn(qx, qx), __fmul_rn(qy, qy)),
                         __fmul_rn(qz, qz));
    int cnt = 0;
    for (int j = lane; j < n; j += 64) {
        float u = pair_metric(qx, qy, qz, q2, data[3 * j], data[3 * j + 1], data[3 * j + 2]);
        if (u <= T) cnt++;
    }
    for (int off = 32; off > 0; off >>= 1) cnt += __shfl_down(cnt, off, 64);
    if (lane == 0) counts[q] = cnt;
}

__global__ __launch_bounds__(1024) void scan_kernel2(const int* __restrict__ counts,
                                                     int* __restrict__ rs, int m) {
    __shared__ int part[1024];
    int t = threadIdx.x;
    int base = t * 8;
    int c[8];
    int s = 0;
    for (int k = 0; k < 8; ++k) {
        int p = base + k;
        c[k] = (p < m) ? counts[p] : 0;
        s += c[k];
    }
    part[t] = s;
    __syncthreads();
    for (int off = 1; off < 1024; off <<= 1) {
        int v = 0;
        if (t >= off) v = part[t - off];
        __syncthreads();
        if (t >= off) part[t] += v;
        __syncthreads();
    }
    int run = (t == 0) ? 0 : part[t - 1];
    for (int k = 0; k < 8; ++k) {
        int p = base + k;
        if (p < m) rs[p] = run;
        run += c[k];
    }
    if (t == 1023) rs[m] = part[1023];
}

__global__ __launch_bounds__(256) void emit_kernel(
    const float* __restrict__ data, const float* __restrict__ queries,
    const float* __restrict__ radius_p, int n, int m,
    const int* __restrict__ row_splits, int* __restrict__ out_idx) {
    int q = (blockIdx.x * blockDim.x + threadIdx.x) >> 6;
    int lane = threadIdx.x & 63;
    if (q >= m) return;
    float r = radius_p[0];
    float T = sq_threshold(r);
    float qx = queries[3 * q + 0], qy = queries[3 * q + 1], qz = queries[3 * q + 2];
    float q2 = __fadd_rn(__fadd_rn(__fmul_rn(qx, qx), __fmul_rn(qy, qy)),
                         __fmul_rn(qz, qz));
    int base = row_splits[q];
    unsigned long long lane_mask_lt = (lane == 0) ? 0ULL : (~0ULL >> (64 - lane));
    for (int j0 = 0; j0 < n; j0 += 64) {
        int j = j0 + lane;
        bool pred = false;
        if (j < n) {
            float u = pair_metric(qx, qy, qz, q2, data[3 * j], data[3 * j + 1], data[3 * j + 2]);
            pred = (u <= T);
        }
        unsigned long long mask = __ballot(pred);
        if (pred) {
            int pos = base + __popcll(mask & lane_mask_lt);
            out_idx[pos] = j;
        }
        base += __popcll(mask);
    }
}

// ===========================================================================

extern "C" void kernel_launch(void* const* d_in, const int* in_sizes, int n_in,
                              void* d_out, int out_size, void* d_ws, size_t ws_size,
                              hipStream_t stream) {
    const float* data = (const float*)d_in[0];
    const float* queries = (const float*)d_in[1];
    const float* radius = (const float*)d_in[2];
    int n = in_sizes[0] / 3;
    int m = in_sizes[1] / 3;
    int* out = (int*)d_out;
    size_t idx_count = (size_t)m * (size_t)n;
    int* row = out + idx_count;  // m+1 ints

    // ws layout: masks (8MB, query-major) | counts (32KB)
    size_t mask_bytes = (size_t)N8 * 128 * 8;
    size_t need = mask_bytes + N8 * 4;
    bool fast = (n == N8) && (m == N8) && (ws_size >= need);

    if (fast) {
        unsigned long long* masks = (unsigned long long*)d_ws;
        int* counts = (int*)((char*)d_ws + mask_bytes);
        hipMemsetAsync(counts, 0, N8 * sizeof(int), stream);
        fused_interleave<<<2048, 256, 0, stream>>>(data, queries, radius, out,
                                                   masks, counts);
        scanemit_fill_tail<<<2048, 256, 0, stream>>>(masks, counts, out, row);
    } else {
        fill_kernel<<<2048, 256, 0, stream>>>(out, idx_count);
        int blocks = (m * 64 + 255) / 256;
        count_kernel<<<blocks, 256, 0, stream>>>(data, queries, radius, n, m, row);
        scan_kernel2<<<1, 1024, 0, stream>>>(row, row, m);
        emit_kernel<<<blocks, 256, 0, stream>>>(data, queries, radius, n, m, row, out);
    }
}